// Round 2
// baseline (102.217 us; speedup 1.0000x reference)
//
#include <hip/hip_runtime.h>
#include <hip/hip_bf16.h>

// NT-Xent (SimCLR) fused loss, MI355X gfx950. Round 10: occupancy + pipeline.
// r9 counters: MfmaUtil 6.6%, VALUBusy 20%, HBM 6.5%, Occupancy 13% ->
// latency-bound at 2 waves/SIMD with 2 barriers/tile. Changes:
// - 512-thread blocks (8 waves, 4x2 quadrants, 32x64 per-wave subtile);
//   LDS still 64KB -> 2 blocks/CU -> 16 waves/CU (4/SIMD), 2x occupancy.
// - Double-buffered B at zero LDS cost: A's buffer is dead after the
//   one-time A-fragment register read; reuse it as B buf[1]. Stage(t+1)
//   issues at the TOP of tile t -> full-tile overlap window; one barrier
//   per tile instead of two.
// - finalize parallelized (16 blocks, atomicAdd; out zeroed in normalize).
// Work assignment (grid 8x64, 4/5 tiles per block), fp8 MFMA path, XOR
// swizzle, register row-sums unchanged from r9. Known deferred defect:
// 32 blocks do 5 tiles (tail) -- revisit with counters.
//
// ws layout: [S: N floats][pos: N floats][zn8: N*D fp8 bytes]

#define N_TOT 8192
#define BATCH 4096
#define DIM   256                    // fp8 bytes per row
#define NT_TILES 64                  // 8192 / 128

typedef int   v8i32 __attribute__((ext_vector_type(8)));
typedef float f32x4 __attribute__((ext_vector_type(4)));

__device__ __forceinline__ void load_lds16(const void* g, void* l) {
  __builtin_amdgcn_global_load_lds(
      (const __attribute__((address_space(1))) unsigned int*)g,
      (__attribute__((address_space(3))) unsigned int*)l,
      16, 0, 0);
}

// One wave per row: 64 lanes x float4 -> 4 fp8 bytes/lane. Also zeros S
// and the output accumulator.
__global__ __launch_bounds__(256) void normalize_kernel(
    const float* __restrict__ z, unsigned char* __restrict__ zn8,
    float* __restrict__ S, float* __restrict__ out) {
  const int wave = threadIdx.x >> 6;
  const int lane = threadIdx.x & 63;
  const int row  = blockIdx.x * 4 + wave;
  float4 v = ((const float4*)(z + (size_t)row * DIM))[lane];
  float ss = v.x * v.x + v.y * v.y + v.z * v.z + v.w * v.w;
#pragma unroll
  for (int m = 1; m <= 32; m <<= 1) ss += __shfl_xor(ss, m);
  float inv = 1.0f / sqrtf(ss);
  int p01 = __builtin_amdgcn_cvt_pk_fp8_f32(v.x * inv, v.y * inv, 0, false);
  int p23 = __builtin_amdgcn_cvt_pk_fp8_f32(v.z * inv, v.w * inv, 0, false);
  unsigned int packed =
      ((unsigned int)p01 & 0xffffu) | ((unsigned int)p23 << 16);
  ((unsigned int*)(zn8 + (size_t)row * DIM))[lane] = packed;
  if (threadIdx.x < 4) S[blockIdx.x * 4 + threadIdx.x] = 0.0f;
  if (blockIdx.x == 0 && threadIdx.x == 0) out[0] = 0.0f;
}

// Stage a 128-row band (full K = 256 B/row = 32 KB) into LDS, 8 waves.
// Per issue a wave writes 4 rows x 256 B = 1 KB; lane l -> row +(l>>4),
// LDS 16B-chunk (l&15); fetches global chunk (l&15)^(row&15) (XOR swizzle
// keeps fragment ds_read_b128 bank-balanced; measured 0 conflicts).
// LDS dest offset == wave-uniform base + lane*16 (global_load_lds rule).
__device__ __forceinline__ void stage_band(
    const unsigned char* __restrict__ zn8, unsigned char* lds, int band,
    int wave, int lane) {
  const int srow = lane >> 4;          // 0..3
  const int slds = lane & 15;          // LDS chunk within row
  const size_t r0 = (size_t)band * 128;
#pragma unroll
  for (int t = 0; t < 4; ++t) {
    const int rloc = wave * 16 + t * 4 + srow;          // 0..127
    const int gch  = slds ^ (rloc & 15);                // swizzled source
    load_lds16(zn8 + (r0 + rloc) * DIM + gch * 16,
               lds + rloc * 256 + slds * 16);
  }
}

// Read one (row, k-half) fragment (32 bytes) from a swizzled band.
__device__ __forceinline__ v8i32 read_frag(const unsigned char* lds, int row,
                                           int h, int quad) {
  const int4* R = (const int4*)(lds + (size_t)row * 256);
  const int base = 8 * h + 2 * quad;   // even global chunk of this lane
  const int cc = row & 15;
  int4 lo = R[base ^ cc];
  int4 hi = R[(base + 1) ^ cc];
  return (v8i32){lo.x, lo.y, lo.z, lo.w, hi.x, hi.y, hi.z, hi.w};
}

// Tile epilogue. MODE 0 = plain, 1 = diagonal tile (mask self-sim, skip
// column flush), 2 = partner tile (jj==32: emit pos logits).
// Row sums accumulate into rs[8] (flushed once per block by caller);
// column sums reduce + atomic per tile (columns change every tile).
template <int MODE>
__device__ __forceinline__ void epilogue_tile(
    const f32x4 (&acc)[2][4], float (&rs)[8], float* __restrict__ S,
    float* __restrict__ pos, int rb, int cbt, int wm, int wn, int c,
    int quad) {
  float cs[4] = {0.f, 0.f, 0.f, 0.f};
#pragma unroll
  for (int fm = 0; fm < 2; ++fm) {
#pragma unroll
    for (int r = 0; r < 4; ++r) {
      const int grow = rb * 128 + wm * 32 + fm * 16 + quad * 4 + r;
#pragma unroll
      for (int fn = 0; fn < 4; ++fn) {
        const int gcol = cbt * 128 + wn * 64 + fn * 16 + c;
        // exp(acc*10) == exp2(acc * 10*log2(e))
        float e = exp2f(acc[fm][fn][r] * 14.4269504089f);
        if (MODE == 1 && gcol == grow) e = 0.f;   // exclude self-similarity
        if (MODE == 2 && ((gcol ^ grow) == BATCH)) {
          const float logit = acc[fm][fn][r] * 10.0f;
          pos[grow] = logit;                       // unique writer/elem
          pos[gcol] = logit;                       // sim symmetric
        }
        rs[fm * 4 + r] += e;
        cs[fn] += e;
      }
    }
  }
  if (MODE != 1) {
    // column sums -> S[col] (transpose contribution of this tile)
#pragma unroll
    for (int fn = 0; fn < 4; ++fn) {
      cs[fn] += __shfl_xor(cs[fn], 16);
      cs[fn] += __shfl_xor(cs[fn], 32);
    }
    if (quad == 0) {
#pragma unroll
      for (int fn = 0; fn < 4; ++fn)
        atomicAdd(&S[cbt * 128 + wn * 64 + fn * 16 + c], cs[fn]);
    }
  }
}

__global__ __launch_bounds__(512, 4) void simclr_tile_kernel(
    const unsigned char* __restrict__ zn8, float* __restrict__ S,
    float* __restrict__ pos) {
  const int g = blockIdx.x;                    // j-group 0..7
  const int rb = blockIdx.y;                   // row band 0..63 (A, fixed)
  const int tid = threadIdx.x;
  const int wave = tid >> 6, lane = tid & 63;
  const int wm = wave >> 1, wn = wave & 1;     // 4x2 quadrants: 32x64/wave
  const int c = lane & 15, quad = lane >> 4;   // MFMA lane coords

  // Two 32KB band buffers. L[1] holds A only until its fragments are in
  // registers, then becomes B's second buffer (double-buffer, no extra LDS).
  __shared__ alignas(16) unsigned char L[2][128 * 256];   // 64 KB

  const int ntile = (g == 0 && rb < 32) ? 5 : 4;  // g0 also does j=32

  stage_band(zn8, L[0], (rb + g * 4) & 63, wave, lane);   // B for tile 0
  stage_band(zn8, L[1], rb, wave, lane);                  // A (transient)
  __syncthreads();

  // A-fragments -> registers, reused across all tiles of this block.
  v8i32 af[2][2];
#pragma unroll
  for (int f = 0; f < 2; ++f)
#pragma unroll
    for (int h = 0; h < 2; ++h)
      af[f][h] = read_frag(L[1], wm * 32 + f * 16 + c, h, quad);
  __syncthreads();   // all waves done with A; L[1] is now B buf[1]

  // Per-row exp-sum partials, accumulated across ALL tiles of this block
  // (the wave's 8 output rows are the same for every tile).
  float rs[8];
#pragma unroll
  for (int i = 0; i < 8; ++i) rs[i] = 0.f;

  for (int t = 0; t < ntile; ++t) {
    const int jj = (t == 4) ? 32 : (g * 4 + t);
    const int cbt = (rb + jj) & 63;

    // Issue next-tile staging FIRST: lands in the other buffer (last read
    // at tile t-1, safe since the barrier ending t-1), drains at this
    // tile's end barrier -> full-tile latency window.
    if (t + 1 < ntile) {
      const int jn = (t + 1 == 4) ? 32 : (g * 4 + t + 1);
      stage_band(zn8, L[(t + 1) & 1], (rb + jn) & 63, wave, lane);
    }

    const unsigned char* Bcur = L[t & 1];
    f32x4 acc[2][4];
#pragma unroll
    for (int i = 0; i < 2; ++i)
#pragma unroll
      for (int k = 0; k < 4; ++k) acc[i][k] = (f32x4){0.f, 0.f, 0.f, 0.f};

#pragma unroll
    for (int h = 0; h < 2; ++h) {
      v8i32 bfr[4];
#pragma unroll
      for (int f = 0; f < 4; ++f)
        bfr[f] = read_frag(Bcur, wn * 64 + f * 16 + c, h, quad);
#pragma unroll
      for (int fm = 0; fm < 2; ++fm)
#pragma unroll
        for (int fn = 0; fn < 4; ++fn)
          acc[fm][fn] = __builtin_amdgcn_mfma_scale_f32_16x16x128_f8f6f4(
              af[fm][h], bfr[fn], acc[fm][fn],
              0, 0,                 // cbsz = fp8(A), blgp = fp8(B)
              0, 0x7f,              // opsel_a, scale_a = E8M0 1.0
              0, 0x7f);             // opsel_b, scale_b = E8M0 1.0
    }

    // Epilogue, specialized per tile kind (uniform branch).
    if (g == 0 && t == 0)
      epilogue_tile<1>(acc, rs, S, pos, rb, cbt, wm, wn, c, quad);
    else if (t == 4)
      epilogue_tile<2>(acc, rs, S, pos, rb, cbt, wm, wn, c, quad);
    else
      epilogue_tile<0>(acc, rs, S, pos, rb, cbt, wm, wn, c, quad);

    // Single barrier/tile: drains this wave's staging loads (vmcnt) and
    // guarantees all waves are done reading Bcur before it is restaged.
    __syncthreads();
  }

  // Flush per-row sums: one shuffle-reduce + atomic per row, once per block.
#pragma unroll
  for (int fm = 0; fm < 2; ++fm) {
#pragma unroll
    for (int r = 0; r < 4; ++r) {
      float s = rs[fm * 4 + r];
      s += __shfl_xor(s, 1);
      s += __shfl_xor(s, 2);
      s += __shfl_xor(s, 4);
      s += __shfl_xor(s, 8);
      if (c == 0) {
        const int grow = rb * 128 + wm * 32 + fm * 16 + quad * 4 + r;
        atomicAdd(&S[grow], s);
      }
    }
  }
}

// loss = mean(log(S_i) - pos_i); 16 blocks, atomic accumulate into out.
__global__ __launch_bounds__(512) void finalize_kernel(
    const float* __restrict__ S, const float* __restrict__ pos,
    float* __restrict__ out) {
  const int i = blockIdx.x * 512 + threadIdx.x;
  float a = __logf(S[i]) - pos[i];
#pragma unroll
  for (int m = 1; m <= 32; m <<= 1) a += __shfl_xor(a, m);
  __shared__ float red[8];
  if ((threadIdx.x & 63) == 0) red[threadIdx.x >> 6] = a;
  __syncthreads();
  if (threadIdx.x < 8) {
    float v = red[threadIdx.x];
    v += __shfl_xor(v, 1);
    v += __shfl_xor(v, 2);
    v += __shfl_xor(v, 4);
    if (threadIdx.x == 0) atomicAdd(out, v * (1.0f / (float)N_TOT));
  }
}

extern "C" void kernel_launch(void* const* d_in, const int* in_sizes, int n_in,
                              void* d_out, int out_size, void* d_ws,
                              size_t ws_size, hipStream_t stream) {
  const float* z = (const float*)d_in[0];
  float* out = (float*)d_out;
  char* ws = (char*)d_ws;
  float* S = (float*)ws;                                   // N floats
  float* pos = (float*)(ws + N_TOT * sizeof(float));       // N floats
  unsigned char* zn8 =
      (unsigned char*)(ws + 2 * N_TOT * sizeof(float));    // N*D fp8

  normalize_kernel<<<N_TOT / 4, 256, 0, stream>>>(z, zn8, S, out);
  dim3 grid(8, NT_TILES);
  simclr_tile_kernel<<<grid, 512, 0, stream>>>(zn8, S, pos);
  finalize_kernel<<<N_TOT / 512, 512, 0, stream>>>(S, pos, out);
}

// Round 3
// 83.675 us; speedup vs baseline: 1.2216x; 1.2216x over previous
//
#include <hip/hip_runtime.h>
#include <hip/hip_bf16.h>

// NT-Xent (SimCLR) fused loss, MI355X gfx950. Round 11: fast exp, r8 shape.
// Post-mortem r9/r10: occupancy doubling (512thr) was NEUTRAL -> not
// latency-bound. r9's regression (42->47us) tracks the __expf -> exp2f
// swap: exp2f w/o fast-math is an OCML libcall (~20 VALU ops) x 33.5M
// calls. This round: back to the measured-best 256-thread 2x2-wave
// structure; exp = __builtin_amdgcn_exp2f (raw v_exp_f32, 1 trans op);
// keep register row-sums (rs[16], one flush/block) and the zero-LDS-cost
// B double-buffer (A's buffer reused; stage(t+1) at top of tile t; ONE
// barrier per tile).
//
// ws layout: [S: N floats][pos: N floats][zn8: N*D fp8 bytes]

#define N_TOT 8192
#define BATCH 4096
#define DIM   256                    // fp8 bytes per row
#define NT_TILES 64                  // 8192 / 128
#define LOG2E_T 14.4269504089f       // 10 * log2(e)  (temperature folded)

typedef int   v8i32 __attribute__((ext_vector_type(8)));
typedef float f32x4 __attribute__((ext_vector_type(4)));

__device__ __forceinline__ void load_lds16(const void* g, void* l) {
  __builtin_amdgcn_global_load_lds(
      (const __attribute__((address_space(1))) unsigned int*)g,
      (__attribute__((address_space(3))) unsigned int*)l,
      16, 0, 0);
}

// One wave per row: 64 lanes x float4 -> 4 fp8 bytes/lane. Also zeros S
// and the output accumulator.
__global__ __launch_bounds__(256) void normalize_kernel(
    const float* __restrict__ z, unsigned char* __restrict__ zn8,
    float* __restrict__ S, float* __restrict__ out) {
  const int wave = threadIdx.x >> 6;
  const int lane = threadIdx.x & 63;
  const int row  = blockIdx.x * 4 + wave;
  float4 v = ((const float4*)(z + (size_t)row * DIM))[lane];
  float ss = v.x * v.x + v.y * v.y + v.z * v.z + v.w * v.w;
#pragma unroll
  for (int m = 1; m <= 32; m <<= 1) ss += __shfl_xor(ss, m);
  float inv = 1.0f / sqrtf(ss);
  int p01 = __builtin_amdgcn_cvt_pk_fp8_f32(v.x * inv, v.y * inv, 0, false);
  int p23 = __builtin_amdgcn_cvt_pk_fp8_f32(v.z * inv, v.w * inv, 0, false);
  unsigned int packed =
      ((unsigned int)p01 & 0xffffu) | ((unsigned int)p23 << 16);
  ((unsigned int*)(zn8 + (size_t)row * DIM))[lane] = packed;
  if (threadIdx.x < 4) S[blockIdx.x * 4 + threadIdx.x] = 0.0f;
  if (blockIdx.x == 0 && threadIdx.x == 0) out[0] = 0.0f;
}

// Stage a 128-row band (full K = 256 B/row = 32 KB) into LDS, 4 waves.
// Per issue a wave writes 4 rows x 256 B = 1 KB; lane l -> row +(l>>4),
// LDS 16B-chunk (l&15); fetches global chunk (l&15)^(row&15) (XOR swizzle
// keeps fragment ds_read_b128 bank-balanced; measured 0 conflicts).
// LDS dest == wave-uniform base + lane*16 (global_load_lds constraint).
__device__ __forceinline__ void stage_band(
    const unsigned char* __restrict__ zn8, unsigned char* lds, int band,
    int wave, int lane) {
  const int srow = lane >> 4;          // 0..3
  const int slds = lane & 15;          // LDS chunk within row
  const size_t r0 = (size_t)band * 128;
#pragma unroll
  for (int t = 0; t < 8; ++t) {
    const int rloc = wave * 32 + t * 4 + srow;          // 0..127
    const int gch  = slds ^ (rloc & 15);                // swizzled source
    load_lds16(zn8 + (r0 + rloc) * DIM + gch * 16,
               lds + rloc * 256 + slds * 16);
  }
}

// Read one (row, k-half) fragment (32 bytes) from a swizzled band.
__device__ __forceinline__ v8i32 read_frag(const unsigned char* lds, int row,
                                           int h, int quad) {
  const int4* R = (const int4*)(lds + (size_t)row * 256);
  const int base = 8 * h + 2 * quad;   // even global chunk of this lane
  const int cc = row & 15;
  int4 lo = R[base ^ cc];
  int4 hi = R[(base + 1) ^ cc];
  return (v8i32){lo.x, lo.y, lo.z, lo.w, hi.x, hi.y, hi.z, hi.w};
}

// Tile epilogue. MODE 0 = plain, 1 = diagonal tile (mask self-sim, skip
// column flush -- diag tile is symmetric, row sums cover it), 2 = partner
// tile (jj==32: emit pos logits).
// Row sums accumulate into rs[16] (flushed once per block by caller);
// column sums reduce + atomic per tile (columns change every tile).
template <int MODE>
__device__ __forceinline__ void epilogue_tile(
    const f32x4 (&acc)[4][4], float (&rs)[16], float* __restrict__ S,
    float* __restrict__ pos, int rb, int cbt, int wm, int wn, int c,
    int quad) {
  float cs[4] = {0.f, 0.f, 0.f, 0.f};
#pragma unroll
  for (int fm = 0; fm < 4; ++fm) {
#pragma unroll
    for (int r = 0; r < 4; ++r) {
      const int grow = rb * 128 + wm * 64 + fm * 16 + quad * 4 + r;
#pragma unroll
      for (int fn = 0; fn < 4; ++fn) {
        const int gcol = cbt * 128 + wn * 64 + fn * 16 + c;
        // exp(acc*10) == exp2(acc * 10*log2(e)); raw v_exp_f32, no libcall
        float e = __builtin_amdgcn_exp2f(acc[fm][fn][r] * LOG2E_T);
        if (MODE == 1 && gcol == grow) e = 0.f;   // exclude self-similarity
        if (MODE == 2 && ((gcol ^ grow) == BATCH)) {
          const float logit = acc[fm][fn][r] * 10.0f;
          pos[grow] = logit;                       // unique writer/elem
          pos[gcol] = logit;                       // sim symmetric
        }
        rs[fm * 4 + r] += e;
        cs[fn] += e;
      }
    }
  }
  if (MODE != 1) {
    // column sums -> S[col] (transpose contribution of this tile)
#pragma unroll
    for (int fn = 0; fn < 4; ++fn) {
      cs[fn] += __shfl_xor(cs[fn], 16);
      cs[fn] += __shfl_xor(cs[fn], 32);
    }
    if (quad == 0) {
#pragma unroll
      for (int fn = 0; fn < 4; ++fn)
        atomicAdd(&S[cbt * 128 + wn * 64 + fn * 16 + c], cs[fn]);
    }
  }
}

__global__ __launch_bounds__(256, 2) void simclr_tile_kernel(
    const unsigned char* __restrict__ zn8, float* __restrict__ S,
    float* __restrict__ pos) {
  const int g = blockIdx.x;                    // j-group 0..7
  const int rb = blockIdx.y;                   // row band 0..63 (A, fixed)
  const int tid = threadIdx.x;
  const int wave = tid >> 6, lane = tid & 63;
  const int wm = wave >> 1, wn = wave & 1;     // wave quadrant (2x2)
  const int c = lane & 15, quad = lane >> 4;   // MFMA lane coords

  // Two 32KB band buffers. L[1] holds A only until its fragments are in
  // registers, then becomes B's second buffer (double-buffer, no extra LDS).
  __shared__ alignas(16) unsigned char L[2][128 * 256];   // 64 KB

  const int ntile = (g == 0 && rb < 32) ? 5 : 4;  // g0 also does j=32

  stage_band(zn8, L[0], (rb + g * 4) & 63, wave, lane);   // B for tile 0
  stage_band(zn8, L[1], rb, wave, lane);                  // A (transient)
  __syncthreads();

  // A-fragments -> registers, reused across all tiles of this block.
  v8i32 af[4][2];
#pragma unroll
  for (int f = 0; f < 4; ++f)
#pragma unroll
    for (int h = 0; h < 2; ++h)
      af[f][h] = read_frag(L[1], wm * 64 + f * 16 + c, h, quad);
  __syncthreads();   // all waves done with A; L[1] is now B buf[1]

  // Per-row exp-sum partials, accumulated across ALL tiles of this block
  // (the wave's 16 output rows are the same for every tile).
  float rs[16];
#pragma unroll
  for (int i = 0; i < 16; ++i) rs[i] = 0.f;

  for (int t = 0; t < ntile; ++t) {
    const int jj = (t == 4) ? 32 : (g * 4 + t);
    const int cbt = (rb + jj) & 63;

    // Issue next-tile staging FIRST into the other buffer (last read at
    // tile t-1, safe since the barrier ending t-1); drains at this tile's
    // end barrier -> full-tile latency window.
    if (t + 1 < ntile) {
      const int jn = (t + 1 == 4) ? 32 : (g * 4 + t + 1);
      stage_band(zn8, L[(t + 1) & 1], (rb + jn) & 63, wave, lane);
    }

    const unsigned char* Bcur = L[t & 1];
    f32x4 acc[4][4];
#pragma unroll
    for (int i = 0; i < 4; ++i)
#pragma unroll
      for (int k = 0; k < 4; ++k) acc[i][k] = (f32x4){0.f, 0.f, 0.f, 0.f};

#pragma unroll
    for (int h = 0; h < 2; ++h) {
      v8i32 bfr[4];
#pragma unroll
      for (int f = 0; f < 4; ++f)
        bfr[f] = read_frag(Bcur, wn * 64 + f * 16 + c, h, quad);
#pragma unroll
      for (int fm = 0; fm < 4; ++fm)
#pragma unroll
        for (int fn = 0; fn < 4; ++fn)
          acc[fm][fn] = __builtin_amdgcn_mfma_scale_f32_16x16x128_f8f6f4(
              af[fm][h], bfr[fn], acc[fm][fn],
              0, 0,                 // cbsz = fp8(A), blgp = fp8(B)
              0, 0x7f,              // opsel_a, scale_a = E8M0 1.0
              0, 0x7f);             // opsel_b, scale_b = E8M0 1.0
    }

    // Epilogue, specialized per tile kind (uniform branch).
    if (g == 0 && t == 0)
      epilogue_tile<1>(acc, rs, S, pos, rb, cbt, wm, wn, c, quad);
    else if (t == 4)
      epilogue_tile<2>(acc, rs, S, pos, rb, cbt, wm, wn, c, quad);
    else
      epilogue_tile<0>(acc, rs, S, pos, rb, cbt, wm, wn, c, quad);

    // Single barrier/tile: drains this wave's staging loads (vmcnt) and
    // guarantees all waves are done reading Bcur before it is restaged.
    __syncthreads();
  }

  // Flush per-row sums: one shuffle-reduce + atomic per row, once per block.
#pragma unroll
  for (int fm = 0; fm < 4; ++fm) {
#pragma unroll
    for (int r = 0; r < 4; ++r) {
      float s = rs[fm * 4 + r];
      s += __shfl_xor(s, 1);
      s += __shfl_xor(s, 2);
      s += __shfl_xor(s, 4);
      s += __shfl_xor(s, 8);
      if (c == 0) {
        const int grow = rb * 128 + wm * 64 + fm * 16 + quad * 4 + r;
        atomicAdd(&S[grow], s);
      }
    }
  }
}

// loss = mean(log(S_i) - pos_i); 16 blocks, atomic accumulate into out.
__global__ __launch_bounds__(512) void finalize_kernel(
    const float* __restrict__ S, const float* __restrict__ pos,
    float* __restrict__ out) {
  const int i = blockIdx.x * 512 + threadIdx.x;
  float a = __logf(S[i]) - pos[i];
#pragma unroll
  for (int m = 1; m <= 32; m <<= 1) a += __shfl_xor(a, m);
  __shared__ float red[8];
  if ((threadIdx.x & 63) == 0) red[threadIdx.x >> 6] = a;
  __syncthreads();
  if (threadIdx.x < 8) {
    float v = red[threadIdx.x];
    v += __shfl_xor(v, 1);
    v += __shfl_xor(v, 2);
    v += __shfl_xor(v, 4);
    if (threadIdx.x == 0) atomicAdd(out, v * (1.0f / (float)N_TOT));
  }
}

extern "C" void kernel_launch(void* const* d_in, const int* in_sizes, int n_in,
                              void* d_out, int out_size, void* d_ws,
                              size_t ws_size, hipStream_t stream) {
  const float* z = (const float*)d_in[0];
  float* out = (float*)d_out;
  char* ws = (char*)d_ws;
  float* S = (float*)ws;                                   // N floats
  float* pos = (float*)(ws + N_TOT * sizeof(float));       // N floats
  unsigned char* zn8 =
      (unsigned char*)(ws + 2 * N_TOT * sizeof(float));    // N*D fp8

  normalize_kernel<<<N_TOT / 4, 256, 0, stream>>>(z, zn8, S, out);
  dim3 grid(8, NT_TILES);
  simclr_tile_kernel<<<grid, 256, 0, stream>>>(zn8, S, pos);
  finalize_kernel<<<N_TOT / 512, 512, 0, stream>>>(S, pos, out);
}